// Round 9
// baseline (77.312 us; speedup 1.0000x reference)
//
#include <hip/hip_runtime.h>

#define OUT_DIM 128
#define CHUNK_LG 14
#define CHUNK (1 << CHUNK_LG)   // 16384 nodes per LDS chunk = 64 KB
#define PB 48                   // blocks per chunk in chunkmax
#define EPB 4096                // edges per bin-block (16 KB LDS staging)
#define NCH_MAX 8

typedef int          vint4  __attribute__((ext_vector_type(4)));
typedef unsigned int vuint4 __attribute__((ext_vector_type(4)));
typedef unsigned int u32;

// Round-to-nearest bf16 of d>=0, keep low 15 bits (sign always 0).
// Order-preserving for d>=0. enc15(0)=0.
__device__ __forceinline__ u32 enc15(float d) {
    u32 b = __float_as_uint(d);
    b += 0x7FFFu + ((b >> 16) & 1u);
    return (b >> 16) & 0x7FFFu;
}

// --- kernel 1: p[i] = nodes[i]·W_theta ; meanW ; zero bucket cursors
__global__ void init_kernel(float* __restrict__ p, float* __restrict__ meanW,
                            u32* __restrict__ cursor,
                            const float* __restrict__ nodes,
                            const float* __restrict__ Wt,
                            const float* __restrict__ W_phi, int n) {
    int i = blockIdx.x * blockDim.x + threadIdx.x;
    if (i < n) {
        float x = nodes[3 * i], y = nodes[3 * i + 1], z = nodes[3 * i + 2];
        p[i] = x * Wt[0] + y * Wt[1] + z * Wt[2];
    }
    if (blockIdx.x == 0) {
        if (threadIdx.x < NCH_MAX) cursor[threadIdx.x] = 0;  // MUST re-zero every launch (graph replay)
        if (threadIdx.x == 0) {
            float s = 0.0f;
            #pragma unroll
            for (int j = 0; j < OUT_DIM; ++j) s += W_phi[j];
            *meanW = s / (float)OUT_DIM;
        }
    }
}

// --- kernel 2: fused encode + bin. Each block stages EPB keys in LDS,
// histograms, reserves bucket space with ONE global atomicAdd per chunk,
// then scatters. Bucket c lives at binned[c*Epad .. ). Order within a
// bucket is nondeterministic -> irrelevant (max-reduce downstream).
__global__ void bin_kernel(const float* __restrict__ p,
                           const int* __restrict__ row,
                           const int* __restrict__ col,
                           u32* __restrict__ binned, u32* __restrict__ cursor,
                           int E, int Epad) {
    __shared__ u32 keys[EPB];
    __shared__ u32 cnt[NCH_MAX];
    __shared__ u32 base[NCH_MAX];
    if (threadIdx.x < NCH_MAX) cnt[threadIdx.x] = 0;
    __syncthreads();

    int s = blockIdx.x * EPB;
    int nk = min(EPB, E - s);

    // phase A: load + encode into LDS (4 keys/thread/round, 4 rounds)
    #pragma unroll
    for (int r = 0; r < EPB / (256 * 4); ++r) {
        int li  = r * 1024 + (int)threadIdx.x * 4;
        int idx = s + li;
        if (idx + 3 < E) {
            vint4 rr = __builtin_nontemporal_load((const vint4*)(row + idx));
            vint4 cc = __builtin_nontemporal_load((const vint4*)(col + idx));
            keys[li + 0] = ((u32)rr.x << 15) | enc15(fabsf(p[rr.x] - p[cc.x]));
            keys[li + 1] = ((u32)rr.y << 15) | enc15(fabsf(p[rr.y] - p[cc.y]));
            keys[li + 2] = ((u32)rr.z << 15) | enc15(fabsf(p[rr.z] - p[cc.z]));
            keys[li + 3] = ((u32)rr.w << 15) | enc15(fabsf(p[rr.w] - p[cc.w]));
        } else {
            for (int j = idx; j < E; ++j)   // at most one thread takes this
                keys[j - s] = ((u32)row[j] << 15) | enc15(fabsf(p[row[j]] - p[col[j]]));
        }
    }
    __syncthreads();

    // phase B: histogram (per-thread regs -> 8 LDS atomics/thread)
    u32 lc[NCH_MAX] = {0, 0, 0, 0, 0, 0, 0, 0};
    for (int i = threadIdx.x; i < nk; i += 256) lc[keys[i] >> (15 + CHUNK_LG)]++;
    #pragma unroll
    for (int c = 0; c < NCH_MAX; ++c)
        if (lc[c]) atomicAdd(&cnt[c], lc[c]);
    __syncthreads();

    // phase C: reserve global space, reset LDS cursors
    if (threadIdx.x < NCH_MAX) {
        u32 t = cnt[threadIdx.x];
        base[threadIdx.x] = t ? atomicAdd(&cursor[threadIdx.x], t) : 0;
        cnt[threadIdx.x] = 0;
    }
    __syncthreads();

    // phase D: scatter to buckets
    for (int i = threadIdx.x; i < nk; i += 256) {
        u32 k = keys[i];
        u32 c = k >> (15 + CHUNK_LG);
        u32 o = atomicAdd(&cnt[c], 1u);
        binned[(size_t)c * Epad + base[c] + o] = k;
    }
}

// --- kernel 3: per-chunk LDS max over its bucket only (each key read ONCE).
// grid = nch*PB. Partials packed 2xu16 per u32.
__global__ void chunkmax_kernel(const u32* __restrict__ binned,
                                const u32* __restrict__ cursor,
                                u32* __restrict__ partial, int Epad) {
    __shared__ u32 lds[CHUNK];
    int c = blockIdx.x / PB;
    int b = blockIdx.x % PB;
    for (int i = threadIdx.x; i < CHUNK; i += blockDim.x) lds[i] = 0;
    __syncthreads();

    int cnt = (int)cursor[c];
    const u32* bk = binned + (size_t)c * Epad;
    int per = (((cnt + PB - 1) / PB) + 3) & ~3;   // 4-aligned slice start
    int s = b * per;
    int e = min(s + per, cnt);

    int nv4 = (e - s) >> 2;                        // full vec4 groups in slice
    const vuint4* bk4 = (const vuint4*)(bk + s);   // s 4-aligned, bk 16B-aligned (Epad%4==0)
    int step = (int)blockDim.x;
    int k = (int)threadIdx.x;
    for (; k + step < nv4; k += 2 * step) {        // 8 keys in flight
        vuint4 a0 = bk4[k];
        vuint4 a1 = bk4[k + step];
        atomicMax(&lds[(a0.x >> 15) & (CHUNK - 1)], a0.x & 0x7FFFu);
        atomicMax(&lds[(a0.y >> 15) & (CHUNK - 1)], a0.y & 0x7FFFu);
        atomicMax(&lds[(a0.z >> 15) & (CHUNK - 1)], a0.z & 0x7FFFu);
        atomicMax(&lds[(a0.w >> 15) & (CHUNK - 1)], a0.w & 0x7FFFu);
        atomicMax(&lds[(a1.x >> 15) & (CHUNK - 1)], a1.x & 0x7FFFu);
        atomicMax(&lds[(a1.y >> 15) & (CHUNK - 1)], a1.y & 0x7FFFu);
        atomicMax(&lds[(a1.z >> 15) & (CHUNK - 1)], a1.z & 0x7FFFu);
        atomicMax(&lds[(a1.w >> 15) & (CHUNK - 1)], a1.w & 0x7FFFu);
    }
    for (; k < nv4; k += step) {
        vuint4 a0 = bk4[k];
        atomicMax(&lds[(a0.x >> 15) & (CHUNK - 1)], a0.x & 0x7FFFu);
        atomicMax(&lds[(a0.y >> 15) & (CHUNK - 1)], a0.y & 0x7FFFu);
        atomicMax(&lds[(a0.z >> 15) & (CHUNK - 1)], a0.z & 0x7FFFu);
        atomicMax(&lds[(a0.w >> 15) & (CHUNK - 1)], a0.w & 0x7FFFu);
    }
    for (int j = s + (nv4 << 2) + (int)threadIdx.x; j < e; j += step) {  // <4 tail
        u32 v = bk[j];
        atomicMax(&lds[(v >> 15) & (CHUNK - 1)], v & 0x7FFFu);
    }
    __syncthreads();
    u32* dst = partial + ((size_t)c * PB + b) * (CHUNK / 2);
    for (int j = threadIdx.x; j < CHUNK / 2; j += blockDim.x)
        dst[j] = lds[2 * j] | (lds[2 * j + 1] << 16);
}

// --- kernel 4: reduce PB packed partials per chunk + final combine
__global__ void reduce_final_kernel(const float* __restrict__ prev,
                                    const u32* __restrict__ partial,
                                    const float* __restrict__ meanW,
                                    float* __restrict__ out, int n) {
    int t = blockIdx.x * blockDim.x + threadIdx.x;
    int i0 = t * 2;
    if (i0 >= n) return;
    int chunk = i0 >> CHUNK_LG;
    int local = i0 & (CHUNK - 1);            // even
    const u32* base = partial + (size_t)chunk * PB * (CHUNK / 2) + (local >> 1);
    u32 mlo = 0, mhi = 0;
    #pragma unroll
    for (int b = 0; b < PB; ++b) {
        u32 v = base[(size_t)b * (CHUNK / 2)];
        mlo = max(mlo, v & 0xFFFFu);
        mhi = max(mhi, v >> 16);
    }
    float mw = *meanW;
    float flo = __uint_as_float(mlo << 16);  // decode bf16 (sign 0)
    float fhi = __uint_as_float(mhi << 16);
    out[i0] = 0.5f * (prev[i0] + mw * flo);
    if (i0 + 1 < n)
        out[i0 + 1] = 0.5f * (prev[i0 + 1] + mw * fhi);
}

// ---------- fallback path (ws too small / N too big): global-atomic version ----------
__global__ void fb_zero_kernel(float* __restrict__ maxd, float* __restrict__ p,
                               float* __restrict__ meanW,
                               const float* __restrict__ nodes,
                               const float* __restrict__ Wt,
                               const float* __restrict__ W_phi, int n) {
    int i = blockIdx.x * blockDim.x + threadIdx.x;
    if (i < n) {
        maxd[i] = 0.0f;
        float x = nodes[3 * i], y = nodes[3 * i + 1], z = nodes[3 * i + 2];
        p[i] = x * Wt[0] + y * Wt[1] + z * Wt[2];
    }
    if (blockIdx.x == 0 && threadIdx.x == 0) {
        float s = 0.0f;
        for (int j = 0; j < OUT_DIM; ++j) s += W_phi[j];
        *meanW = s / (float)OUT_DIM;
    }
}
__global__ void fb_edge_kernel(const float* __restrict__ p,
                               const int* __restrict__ row,
                               const int* __restrict__ col,
                               float* __restrict__ maxd, int E) {
    int t = blockIdx.x * blockDim.x + threadIdx.x;
    int base = t * 4;
    if (base >= E) return;
    if (base + 3 < E) {
        vint4 r = __builtin_nontemporal_load((const vint4*)(row + base));
        vint4 c = __builtin_nontemporal_load((const vint4*)(col + base));
        atomicMax((int*)&maxd[r.x], __float_as_int(fabsf(p[r.x] - p[c.x])));
        atomicMax((int*)&maxd[r.y], __float_as_int(fabsf(p[r.y] - p[c.y])));
        atomicMax((int*)&maxd[r.z], __float_as_int(fabsf(p[r.z] - p[c.z])));
        atomicMax((int*)&maxd[r.w], __float_as_int(fabsf(p[r.w] - p[c.w])));
    } else {
        for (int e = base; e < E; ++e) {
            float d = fabsf(p[row[e]] - p[col[e]]);
            atomicMax((int*)&maxd[row[e]], __float_as_int(d));
        }
    }
}
__global__ void fb_final_kernel(const float* __restrict__ prev,
                                const float* __restrict__ maxd,
                                const float* __restrict__ meanW,
                                float* __restrict__ out, int n) {
    int i = blockIdx.x * blockDim.x + threadIdx.x;
    if (i < n) out[i] = 0.5f * (prev[i] + (*meanW) * maxd[i]);
}

extern "C" void kernel_launch(void* const* d_in, const int* in_sizes, int n_in,
                              void* d_out, int out_size, void* d_ws, size_t ws_size,
                              hipStream_t stream) {
    const float* prev    = (const float*)d_in[0];   // [N]
    const float* nodes   = (const float*)d_in[1];   // [N,3]
    const int*   row     = (const int*)d_in[2];     // [E]
    const int*   col     = (const int*)d_in[3];     // [E]
    const float* W_phi   = (const float*)d_in[4];   // [128]
    const float* W_theta = (const float*)d_in[5];   // [3]

    const int N = in_sizes[0];
    const int E = in_sizes[2];
    float* out = (float*)d_out;
    const int B = 256;

    const int nch  = (N + CHUNK - 1) >> CHUNK_LG;
    const int Epad = (E + 3) & ~3;

    // ws layout: p[N] | binned[nch*Epad] | partial[nch*PB*CHUNK/2] | cursor[8] | meanW
    size_t pBytes    = ((size_t)N * 4 + 15) & ~(size_t)15;
    size_t binBytes  = (size_t)nch * Epad * 4;
    size_t partBytes = (size_t)nch * PB * (CHUNK / 2) * 4;
    size_t need = pBytes + binBytes + partBytes + NCH_MAX * 4 + 4;

    if (ws_size >= need && N <= (1 << 17) && nch <= NCH_MAX) {
        float* p     = (float*)d_ws;
        u32*   binned= (u32*)((char*)d_ws + pBytes);
        u32*   part  = (u32*)((char*)d_ws + pBytes + binBytes);
        u32*   cursor= (u32*)((char*)d_ws + pBytes + binBytes + partBytes);
        float* meanW = (float*)((char*)d_ws + pBytes + binBytes + partBytes + NCH_MAX * 4);

        init_kernel<<<(N + B - 1) / B, B, 0, stream>>>(p, meanW, cursor, nodes, W_theta, W_phi, N);
        int nbB = (E + EPB - 1) / EPB;
        bin_kernel<<<nbB, B, 0, stream>>>(p, row, col, binned, cursor, E, Epad);
        chunkmax_kernel<<<nch * PB, B, 0, stream>>>(binned, cursor, part, Epad);
        int tN = (N + 1) / 2;
        reduce_final_kernel<<<(tN + B - 1) / B, B, 0, stream>>>(prev, part, meanW, out, N);
    } else {
        float* p     = (float*)d_ws;
        float* maxd  = (float*)d_ws + N;
        float* meanW = (float*)d_ws + 2 * (size_t)N;
        fb_zero_kernel<<<(N + B - 1) / B, B, 0, stream>>>(maxd, p, meanW, nodes, W_theta, W_phi, N);
        int tE = (E + 3) / 4;
        fb_edge_kernel<<<(tE + B - 1) / B, B, 0, stream>>>(p, row, col, maxd, E);
        fb_final_kernel<<<(N + B - 1) / B, B, 0, stream>>>(prev, maxd, meanW, out, N);
    }
}